// Round 9
// baseline (369.008 us; speedup 1.0000x reference)
//
#include <hip/hip_runtime.h>
#include <hip/hip_bf16.h>
#include <cstdint>
#include <cstddef>

#define MDIM 4096
#define NDIM 4096
#define KDIM 4096

#define BM 256
#define BN 256
#define BK 64
#define NT (KDIM / BK)   // 64 K-tiles (even)

typedef __bf16 bf16_t;
typedef bf16_t bf16x8 __attribute__((ext_vector_type(8)));
typedef float f32x4 __attribute__((ext_vector_type(4)));

#define GLDS16(gsrc, ldst)                                                   \
    __builtin_amdgcn_global_load_lds(                                        \
        (__attribute__((address_space(1))) void*)(gsrc),                     \
        (__attribute__((address_space(3))) void*)(ldst), 16, 0, 0)

#define BAR()   __builtin_amdgcn_s_barrier()
#define VM4()   asm volatile("s_waitcnt vmcnt(4)" ::: "memory")
#define VM0()   asm volatile("s_waitcnt vmcnt(0)" ::: "memory")
#define PRIO1() __builtin_amdgcn_s_setprio(1)
#define PRIO0() __builtin_amdgcn_s_setprio(0)

// Full 3-bit XOR swizzle for 128B-row tiles: byte ^= (row&7)<<4.
// Verified round 3: SQ_LDS_BANK_CONFLICT -> 0.
__device__ __forceinline__ int swz(int q) { return q ^ (((q >> 7) & 7) << 4); }

// ---------------- fp32 -> bf16 conversion pass ----------------
__global__ void cvt_f32_to_bf16(const float* __restrict__ src,
                                bf16_t* __restrict__ dst, int n) {
    int idx = (blockIdx.x * blockDim.x + threadIdx.x) * 8;
    int stride = gridDim.x * blockDim.x * 8;
    for (int i = idx; i < n; i += stride) {
        const float4* s = reinterpret_cast<const float4*>(src + i);
        float4 a = s[0];
        float4 b = s[1];
        bf16x8 o;
        o[0] = (bf16_t)a.x; o[1] = (bf16_t)a.y;
        o[2] = (bf16_t)a.z; o[3] = (bf16_t)a.w;
        o[4] = (bf16_t)b.x; o[5] = (bf16_t)b.y;
        o[6] = (bf16_t)b.z; o[7] = (bf16_t)b.w;
        *reinterpret_cast<bf16x8*>(dst + i) = o;
    }
}

// ------ 256x256 bf16 NT-GEMM: R3 skeleton + one-phase MFMA OFFSET ---------
// Evidence matrix: R3 (lgkm0 drain) = 128us; same-phase dataflow with
// compiler waits (R4/R8) = 151us -> waiting on your OWN same-phase reads is a
// drain no matter how it's spelled.  Fix: every MFMA cluster consumes reads
// issued >= 1 phase earlier, so the compiler's counted lgkmcnt allows the
// fresh phase's reads to stay outstanding and their queue drains UNDER the
// cluster.  Quadrant stream offset by one phase (tail quadrant after loop):
//   P1: reads A0,B0(t)(12); stage A1(t+1,^1); BAR; Q10(t-1)[oldA1,oldB0]; BAR
//   P2: reads B1(t)(4);     stage B1(t+1,^1); BAR; Q00(t)[A0,B0];         BAR
//   P3: reads A1(t)(8);     stage B0(t+2,cur);BAR; Q01(t)[A0,B1];         BAR
//   P4:                     stage A0(t+2,cur);BAR; Q11(t)[A1,B1]; VM; BAR
// WAR (>=1 barrier between proven reader completion and overwrite):
//   B0 slot: consumed by Q00@P2 < P2 closing BAR < stage@P3.  A0: consumed
//   Q01@P3 < stage@P4.  A1 slot: consumed Q11@P4 < boundary BAR < stage@P1'.
//   B1 slot(^1): consumed Q11@P4(t-1) < boundary < stage@P2.
// RAW: identical vm algebra to R3 -- VM4@P4(t) forces A1,B1(t+1)+older,
// leaves B0,A0(t+2) in flight; tile t+1 reads only after the final BAR.
// Registers: peak 24 live frags (oldA1+oldB0 + fresh A0+B0) = 96 VGPR; acc
// is 128 AGPR (unified file); addressing kept lean to stay under the cap.

#define RD_A(DST, MH, BUF) do {                                              \
  _Pragma("unroll") for (int mi = 0; mi < 4; ++mi)                           \
  _Pragma("unroll") for (int ko = 0; ko < 2; ++ko)                           \
    DST[mi][ko] = *(const bf16x8*)(ldsb + ((BUF) << 16) + aB[ko] +           \
                                   (MH) * 8192 + mi * 2048);                 \
} while (0)

#define RD_B(DST, NH, BUF) do {                                              \
  _Pragma("unroll") for (int ni = 0; ni < 2; ++ni)                           \
  _Pragma("unroll") for (int ko = 0; ko < 2; ++ko)                           \
    DST[ni][ko] = *(const bf16x8*)(ldsb + ((BUF) << 16) + bB[ko] +           \
                                   (NH) * 4096 + ni * 2048);                 \
} while (0)

#define MFMA_Q(ASET, BSET, MH, NH) do {                                      \
  _Pragma("unroll") for (int mi = 0; mi < 4; ++mi)                           \
  _Pragma("unroll") for (int ni = 0; ni < 2; ++ni)                           \
  _Pragma("unroll") for (int ko = 0; ko < 2; ++ko)                           \
    acc[(MH)*4 + mi][(NH)*2 + ni] = __builtin_amdgcn_mfma_f32_16x16x32_bf16( \
        ASET[mi][ko], BSET[ni][ko], acc[(MH)*4 + mi][(NH)*2 + ni], 0, 0, 0); \
} while (0)

// A0C/B0C/B1C/A1C: this tile's operand sets (written); A1P/B0P: previous
// tile's sets (consumed by the offset Q10).  FIRST is a literal 0/1.
#define TILE(T, BUF, A0C, B0C, B1C, A1C, A1P, B0P, FIRST) do {               \
    /* P1 */                                                                 \
    RD_A(A0C, 0, BUF); RD_B(B0C, 0, BUF);                                    \
    if ((T) + 1 < NT) stA((T) + 1, (BUF) ^ 1, 1);                            \
    BAR();                                                                   \
    if (!(FIRST)) { PRIO1(); MFMA_Q(A1P, B0P, 1, 0); PRIO0(); }              \
    BAR();                                                                   \
    /* P2 */                                                                 \
    RD_B(B1C, 1, BUF);                                                       \
    if ((T) + 1 < NT) stB((T) + 1, (BUF) ^ 1, 1);                            \
    BAR();                                                                   \
    PRIO1(); MFMA_Q(A0C, B0C, 0, 0); PRIO0();                                \
    BAR();                                                                   \
    /* P3 */                                                                 \
    RD_A(A1C, 1, BUF);                                                       \
    if ((T) + 2 < NT) stB((T) + 2, (BUF), 0);                                \
    BAR();                                                                   \
    PRIO1(); MFMA_Q(A0C, B1C, 0, 1); PRIO0();                                \
    BAR();                                                                   \
    /* P4 */                                                                 \
    if ((T) + 2 < NT) stA((T) + 2, (BUF), 0);                                \
    BAR();                                                                   \
    PRIO1(); MFMA_Q(A1C, B1C, 1, 1); PRIO0();                                \
    if ((T) < NT - 2) { VM4(); } else { VM0(); }                             \
    BAR();                                                                   \
} while (0)

__global__ __launch_bounds__(512, 2) void gemm256(const bf16_t* __restrict__ A,
                                                  const bf16_t* __restrict__ B,
                                                  const float* __restrict__ beta,
                                                  float* __restrict__ out) {
    extern __shared__ char ldsb[];   // 131072 bytes, dynamic

    const int tid    = threadIdx.x;
    const int wid    = tid >> 6;
    const int lane   = tid & 63;
    const int warp_m = wid >> 2;     // 0..1
    const int warp_n = wid & 3;      // 0..3
    const int lrow   = lane & 15;
    const int kgrp   = lane >> 4;

    // XCD-aware swizzle (grid = 256 = 8 XCDs x 32; bijective)
    const int bid  = blockIdx.x;
    const int sbid = (bid & 7) * 32 + (bid >> 3);
    const int brow = (sbid >> 4) * BM;
    const int bcol = (sbid & 15) * BN;

    // ---- staging precompute (verbatim R3) ----
    const int p0 = tid * 16, p1 = (tid + 512) * 16;
    const int q0 = swz(p0), q1 = swz(p1);
    const int rh0 = q0 >> 7, ce0 = (q0 & 127) >> 1;
    const int rh1 = q1 >> 7, ce1 = (q1 & 127) >> 1;

    const bf16_t* gA = A + (size_t)brow * KDIM;   // uniform -> SGPR
    const bf16_t* gB = B + (size_t)bcol * KDIM;

    int off[2][2];
#pragma unroll
    for (int h = 0; h < 2; ++h) {
        off[h][0] = (h * 128 + rh0) * KDIM + ce0;
        off[h][1] = (h * 128 + rh1) * KDIM + ce1;
    }

    auto stA = [&](int t, int buf, int h) {
        const bf16_t* g = gA + t * BK;
        char* d = ldsb + (buf << 16) + (h << 14);
        GLDS16(g + off[h][0], d + p0);
        GLDS16(g + off[h][1], d + p1);
    };
    auto stB = [&](int t, int buf, int h) {
        const bf16_t* g = gB + t * BK;
        char* d = ldsb + (buf << 16) + ((2 + h) << 14);
        GLDS16(g + off[h][0], d + p0);
        GLDS16(g + off[h][1], d + p1);
    };

    // ---- compressed ds_read lane-bases (identical addresses to R3) ----
    // swz(row*128+kb) = row*128 + (kb ^ ((lrow&7)<<4)) since row&7 == lrow&7.
    const int kx = (lrow & 7) << 4;
    int aB[2], bB[2];
#pragma unroll
    for (int ko = 0; ko < 2; ++ko) {
        const int kb = (ko * 64 + kgrp * 16) ^ kx;
        aB[ko] = (warp_m << 14) + lrow * 128 + kb;
        bB[ko] = ((2 + (warp_n >> 1)) << 14) + ((warp_n & 1) * 64 + lrow) * 128 + kb;
    }

    f32x4 acc[8][4];
#pragma unroll
    for (int i = 0; i < 8; ++i)
#pragma unroll
        for (int j = 0; j < 4; ++j)
            acc[i][j] = (f32x4){0.f, 0.f, 0.f, 0.f};

    // operand sets, even/odd tile parity (all indices compile-time)
    bf16x8 aE0[4][2], aE1[4][2], aO0[4][2], aO1[4][2];
    bf16x8 bE0[2][2], bE1[2][2], bO0[2][2], bO1[2][2];

    // ---- prologue (verbatim R3): tile0 + B0(1),A0(1) staged; force tile0 --
    stA(0, 0, 0); stA(0, 0, 1); stB(0, 0, 0); stB(0, 0, 1);
    stB(1, 1, 0); stA(1, 1, 0);
    VM4();   // tile0's 8 loads retired; B0(1),A0(1) may fly
    BAR();   // publish tile0

    // peel first pair (FIRST=1 skips the offset Q10 of tile -1)
    TILE(0, 0, aE0, bE0, bE1, aE1, aO1, bO0, 1);
    TILE(1, 1, aO0, bO0, bO1, aO1, aE1, bE0, 0);
    for (int t = 2; t < NT; t += 2) {
        TILE(t,     0, aE0, bE0, bE1, aE1, aO1, bO0, 0);
        TILE(t + 1, 1, aO0, bO0, bO1, aO1, aE1, bE0, 0);
    }
    // tail: Q10 of tile NT-1 (odd parity sets)
    PRIO1(); MFMA_Q(aO1, bO0, 1, 0); PRIO0();

    // ---- epilogue: relu(1 - beta + acc) ----
    const float bias = 1.0f - beta[0];
    float* outp = out + (size_t)(brow + warp_m * 128) * NDIM + bcol + warp_n * 64;
#pragma unroll
    for (int mi = 0; mi < 8; ++mi)
#pragma unroll
        for (int ni = 0; ni < 4; ++ni)
#pragma unroll
            for (int j = 0; j < 4; ++j) {
                const int r = mi * 16 + kgrp * 4 + j;   // C/D: row=(lane>>4)*4+reg
                const int c = ni * 16 + lrow;           //      col=lane&15
                outp[(size_t)r * NDIM + c] = fmaxf(acc[mi][ni][j] + bias, 0.0f);
            }
}

// ---------------- fp32 fallback (only if ws too small) ----------------
__global__ void gemm_f32_fallback(const float* __restrict__ A,
                                  const float* __restrict__ B,
                                  const float* __restrict__ beta,
                                  float* __restrict__ out) {
    __shared__ float sA[16][17];
    __shared__ float sB[16][17];
    const int tx = threadIdx.x, ty = threadIdx.y;
    const int m = blockIdx.y * 16 + ty;
    const int n = blockIdx.x * 16 + tx;
    float acc = 0.f;
    for (int k0 = 0; k0 < KDIM; k0 += 16) {
        sA[ty][tx] = A[(size_t)m * KDIM + k0 + tx];
        sB[ty][tx] = B[(size_t)(blockIdx.x * 16 + ty) * KDIM + k0 + tx];
        __syncthreads();
#pragma unroll
        for (int k = 0; k < 16; ++k)
            acc += sA[ty][k] * sB[tx][k];
        __syncthreads();
    }
    float v = acc + 1.0f - beta[0];
    out[(size_t)m * NDIM + n] = fmaxf(v, 0.f);
}

extern "C" void kernel_launch(void* const* d_in, const int* in_sizes, int n_in,
                              void* d_out, int out_size, void* d_ws, size_t ws_size,
                              hipStream_t stream) {
    const float* x    = (const float*)d_in[0];
    const float* w    = (const float*)d_in[1];
    const float* beta = (const float*)d_in[2];
    float* out        = (float*)d_out;

    const size_t nelem = (size_t)MDIM * (size_t)KDIM;   // per matrix
    const size_t need  = 2 * nelem * sizeof(bf16_t);    // 64 MB

    if (ws_size >= need) {
        bf16_t* xb = (bf16_t*)d_ws;
        bf16_t* wb = xb + nelem;
        hipFuncSetAttribute((const void*)gemm256,
                            hipFuncAttributeMaxDynamicSharedMemorySize, 131072);
        cvt_f32_to_bf16<<<2048, 256, 0, stream>>>(x, xb, (int)nelem);
        cvt_f32_to_bf16<<<2048, 256, 0, stream>>>(w, wb, (int)nelem);
        gemm256<<<256, 512, 131072, stream>>>(xb, wb, beta, out);
    } else {
        dim3 grid(NDIM / 16, MDIM / 16);
        gemm_f32_fallback<<<grid, dim3(16, 16), 0, stream>>>(x, w, beta, out);
    }
}

// Round 10
// 166.603 us; speedup vs baseline: 2.2149x; 2.2149x over previous
//
#include <hip/hip_runtime.h>
#include <hip/hip_bf16.h>
#include <cstdint>
#include <cstddef>

#define MDIM 4096
#define NDIM 4096
#define KDIM 4096

#define BM 256
#define BN 256
#define BK 64
#define NT (KDIM / BK)   // 64 K-tiles (even)

typedef __bf16 bf16_t;
typedef bf16_t bf16x8 __attribute__((ext_vector_type(8)));
typedef float f32x16 __attribute__((ext_vector_type(16)));

#define GLDS16(gsrc, ldst)                                                   \
    __builtin_amdgcn_global_load_lds(                                        \
        (__attribute__((address_space(1))) void*)(gsrc),                     \
        (__attribute__((address_space(3))) void*)(ldst), 16, 0, 0)

#define BAR()   __builtin_amdgcn_s_barrier()
#define LGKM0() asm volatile("s_waitcnt lgkmcnt(0)" ::: "memory")
#define VM4()   asm volatile("s_waitcnt vmcnt(4)" ::: "memory")
#define VM0()   asm volatile("s_waitcnt vmcnt(0)" ::: "memory")
#define PRIO1() __builtin_amdgcn_s_setprio(1)
#define PRIO0() __builtin_amdgcn_s_setprio(0)

// Full 3-bit XOR swizzle for 128B-row tiles: byte ^= (row&7)<<4.
// Verified round 3: SQ_LDS_BANK_CONFLICT -> 0.
__device__ __forceinline__ int swz(int q) { return q ^ (((q >> 7) & 7) << 4); }

// ---------------- fp32 -> bf16 conversion pass ----------------
__global__ void cvt_f32_to_bf16(const float* __restrict__ src,
                                bf16_t* __restrict__ dst, int n) {
    int idx = (blockIdx.x * blockDim.x + threadIdx.x) * 8;
    int stride = gridDim.x * blockDim.x * 8;
    for (int i = idx; i < n; i += stride) {
        const float4* s = reinterpret_cast<const float4*>(src + i);
        float4 a = s[0];
        float4 b = s[1];
        bf16x8 o;
        o[0] = (bf16_t)a.x; o[1] = (bf16_t)a.y;
        o[2] = (bf16_t)a.z; o[3] = (bf16_t)a.w;
        o[4] = (bf16_t)b.x; o[5] = (bf16_t)b.y;
        o[6] = (bf16_t)b.z; o[7] = (bf16_t)b.w;
        *reinterpret_cast<bf16x8*>(dst + i) = o;
    }
}

// ------ 256x256 bf16 NT-GEMM: R3 skeleton verbatim, 32x32x16 MFMA ---------
// Serialized model (validated on R3/R4/R5/R6/R8/R9): tile time = LDS(2304) +
// MFMA + ~0.  MFMA shape swap 16x16x32 -> 32x32x16 cuts the MFMA term
// 2483 -> 2066 cyc/tile (ubench 2382 vs 2075 TF).  NOTHING else changes:
// same barriers, same LGKM0 drain, same stage/vm algebra, same swizzle,
// same 24 b128-reads/wave in 12/4/8/0 phase grouping.
// Per wave (128x64 out): frags (mi 0..3 of 32 rows) x (ni 0..1 of 32 cols)
// x (ks 0..3 of K16).  A/B frag: row=lane&31, k=(lane>>5)*8.  C/D:
// col=lane&31, row=(reg&3)+8*(reg>>2)+4*(lane>>5)  [m74/m101 verified].

#define LOAD_A_HALF(MH, BUF) do {                                            \
  _Pragma("unroll") for (int u = 0; u < 2; ++u)                              \
  _Pragma("unroll") for (int ks = 0; ks < 4; ++ks)                           \
    av[u][ks] = *(const bf16x8*)(ldsb + ((BUF) << 16) + aB[ks] +             \
                                 ((MH)*2 + u) * 4096);                       \
} while (0)

#define LOAD_B_PAIR(NH, BUF) do {                                            \
  _Pragma("unroll") for (int ks = 0; ks < 4; ++ks)                           \
    bv[NH][ks] = *(const bf16x8*)(ldsb + ((BUF) << 16) + bB[ks] +            \
                                  (NH) * 4096);                              \
} while (0)

#define MFMA_QUAD(MH, NH) do {                                               \
  _Pragma("unroll") for (int u = 0; u < 2; ++u)                              \
  _Pragma("unroll") for (int ks = 0; ks < 4; ++ks)                           \
    acc[(MH)*2 + u][NH] = __builtin_amdgcn_mfma_f32_32x32x16_bf16(           \
        av[u][ks], bv[NH][ks], acc[(MH)*2 + u][NH], 0, 0, 0);                \
} while (0)

#define TILE(T, BUF) do {                                                    \
    /* P1 */                                                                 \
    LOAD_A_HALF(0, BUF); LOAD_B_PAIR(0, BUF);                                \
    if ((T) + 1 < NT) stA((T) + 1, (BUF) ^ 1, 1);                            \
    BAR(); LGKM0();                                                          \
    PRIO1(); MFMA_QUAD(0, 0); PRIO0();                                       \
    BAR();                                                                   \
    /* P2 */                                                                 \
    LOAD_B_PAIR(1, BUF);                                                     \
    if ((T) + 1 < NT) stB((T) + 1, (BUF) ^ 1, 1);                            \
    BAR(); LGKM0();                                                          \
    PRIO1(); MFMA_QUAD(0, 1); PRIO0();                                       \
    BAR();                                                                   \
    /* P3 */                                                                 \
    LOAD_A_HALF(1, BUF);                                                     \
    if ((T) + 2 < NT) stB((T) + 2, (BUF), 0);                                \
    BAR(); LGKM0();                                                          \
    PRIO1(); MFMA_QUAD(1, 0); PRIO0();                                       \
    BAR();                                                                   \
    /* P4 */                                                                 \
    if ((T) + 2 < NT) stA((T) + 2, (BUF), 0);                                \
    BAR(); LGKM0();                                                          \
    PRIO1(); MFMA_QUAD(1, 1); PRIO0();                                       \
    if ((T) < NT - 2) { VM4(); } else { VM0(); }                             \
    BAR();                                                                   \
} while (0)

__global__ __launch_bounds__(512, 2) void gemm256(const bf16_t* __restrict__ A,
                                                  const bf16_t* __restrict__ B,
                                                  const float* __restrict__ beta,
                                                  float* __restrict__ out) {
    extern __shared__ char ldsb[];   // 131072 bytes, dynamic

    const int tid    = threadIdx.x;
    const int wid    = tid >> 6;
    const int lane   = tid & 63;
    const int warp_m = wid >> 2;     // 0..1
    const int warp_n = wid & 3;      // 0..3
    const int l31    = lane & 31;    // frag row (A) / col (B,C)
    const int khalf  = lane >> 5;    // k-subgroup: k = khalf*8..+8

    // XCD-aware swizzle (grid = 256 = 8 XCDs x 32; bijective)
    const int bid  = blockIdx.x;
    const int sbid = (bid & 7) * 32 + (bid >> 3);
    const int brow = (sbid >> 4) * BM;
    const int bcol = (sbid & 15) * BN;

    // ---- staging precompute (verbatim R3) ----
    const int p0 = tid * 16, p1 = (tid + 512) * 16;
    const int q0 = swz(p0), q1 = swz(p1);
    const int rh0 = q0 >> 7, ce0 = (q0 & 127) >> 1;
    const int rh1 = q1 >> 7, ce1 = (q1 & 127) >> 1;

    const bf16_t* gA = A + (size_t)brow * KDIM;
    const bf16_t* gB = B + (size_t)bcol * KDIM;

    int off[2][2];
#pragma unroll
    for (int h = 0; h < 2; ++h) {
        off[h][0] = (h * 128 + rh0) * KDIM + ce0;
        off[h][1] = (h * 128 + rh1) * KDIM + ce1;
    }

    auto stA = [&](int t, int buf, int h) {
        const bf16_t* g = gA + t * BK;
        char* d = ldsb + (buf << 16) + (h << 14);
        GLDS16(g + off[h][0], d + p0);
        GLDS16(g + off[h][1], d + p1);
    };
    auto stB = [&](int t, int buf, int h) {
        const bf16_t* g = gB + t * BK;
        char* d = ldsb + (buf << 16) + ((2 + h) << 14);
        GLDS16(g + off[h][0], d + p0);
        GLDS16(g + off[h][1], d + p1);
    };

    // ---- ds_read lane-bases for 32x32x16 frags ----
    // frag (mi, ks): row = mi*32 + l31, kbyte = (ks*16 + khalf*8)*2.
    // swz: row&7 == l31&7 (per-lane const) -> addr = base[ks] + mi*4096.
    const int kx = (l31 & 7) << 4;
    int aB[4], bB[4];
#pragma unroll
    for (int ks = 0; ks < 4; ++ks) {
        const int kb = (ks * 32 + khalf * 16) ^ kx;   // kbyte<128, XOR bit-safe
        aB[ks] = (warp_m << 14) + l31 * 128 + kb;
        bB[ks] = ((2 + (warp_n >> 1)) << 14) + ((warp_n & 1) * 64 + l31) * 128 + kb;
    }

    f32x16 acc[4][2];
#pragma unroll
    for (int i = 0; i < 4; ++i)
#pragma unroll
        for (int j = 0; j < 2; ++j)
            acc[i][j] = (f32x16)(0.f);

    bf16x8 av[2][4];   // current m-half: 2 mi x 4 ks
    bf16x8 bv[2][4];   // both n-frags x 4 ks (pair0 live P1->P3)

    // ---- prologue (verbatim R3): tile0 + B0(1),A0(1) staged; force tile0 --
    stA(0, 0, 0); stA(0, 0, 1); stB(0, 0, 0); stB(0, 0, 1);
    stB(1, 1, 0); stA(1, 1, 0);
    VM4();   // tile0's 8 loads retired; B0(1),A0(1) may fly
    BAR();   // publish tile0

    for (int t = 0; t < NT; t += 2) {
        TILE(t, 0);
        TILE(t + 1, 1);
    }

    // ---- epilogue: relu(1 - beta + acc), 32x32 C/D layout ----
    const float bias = 1.0f - beta[0];
    float* outp = out + (size_t)(brow + warp_m * 128) * NDIM + bcol + warp_n * 64;
#pragma unroll
    for (int mi = 0; mi < 4; ++mi)
#pragma unroll
        for (int ni = 0; ni < 2; ++ni)
#pragma unroll
            for (int reg = 0; reg < 16; ++reg) {
                const int r = mi * 32 + (reg & 3) + 8 * (reg >> 2) + 4 * khalf;
                const int c = ni * 32 + l31;
                outp[(size_t)r * NDIM + c] = fmaxf(acc[mi][ni][reg] + bias, 0.0f);
            }
}

// ---------------- fp32 fallback (only if ws too small) ----------------
__global__ void gemm_f32_fallback(const float* __restrict__ A,
                                  const float* __restrict__ B,
                                  const float* __restrict__ beta,
                                  float* __restrict__ out) {
    __shared__ float sA[16][17];
    __shared__ float sB[16][17];
    const int tx = threadIdx.x, ty = threadIdx.y;
    const int m = blockIdx.y * 16 + ty;
    const int n = blockIdx.x * 16 + tx;
    float acc = 0.f;
    for (int k0 = 0; k0 < KDIM; k0 += 16) {
        sA[ty][tx] = A[(size_t)m * KDIM + k0 + tx];
        sB[ty][tx] = B[(size_t)(blockIdx.x * 16 + ty) * KDIM + k0 + tx];
        __syncthreads();
#pragma unroll
        for (int k = 0; k < 16; ++k)
            acc += sA[ty][k] * sB[tx][k];
        __syncthreads();
    }
    float v = acc + 1.0f - beta[0];
    out[(size_t)m * NDIM + n] = fmaxf(v, 0.f);
}

extern "C" void kernel_launch(void* const* d_in, const int* in_sizes, int n_in,
                              void* d_out, int out_size, void* d_ws, size_t ws_size,
                              hipStream_t stream) {
    const float* x    = (const float*)d_in[0];
    const float* w    = (const float*)d_in[1];
    const float* beta = (const float*)d_in[2];
    float* out        = (float*)d_out;

    const size_t nelem = (size_t)MDIM * (size_t)KDIM;   // per matrix
    const size_t need  = 2 * nelem * sizeof(bf16_t);    // 64 MB

    if (ws_size >= need) {
        bf16_t* xb = (bf16_t*)d_ws;
        bf16_t* wb = xb + nelem;
        hipFuncSetAttribute((const void*)gemm256,
                            hipFuncAttributeMaxDynamicSharedMemorySize, 131072);
        cvt_f32_to_bf16<<<2048, 256, 0, stream>>>(x, xb, (int)nelem);
        cvt_f32_to_bf16<<<2048, 256, 0, stream>>>(w, wb, (int)nelem);
        gemm256<<<256, 512, 131072, stream>>>(xb, wb, beta, out);
    } else {
        dim3 grid(NDIM / 16, MDIM / 16);
        gemm_f32_fallback<<<grid, dim3(16, 16), 0, stream>>>(x, w, beta, out);
    }
}